// Round 1
// baseline (493.889 us; speedup 1.0000x reference)
//
#include <hip/hip_runtime.h>
#include <hip/hip_bf16.h>
#include <stdint.h>

#define M_DIM 4096
#define N_DIM 11008
#define K_DIM 4096
#define KP    (K_DIM / 2)   // packed int32s per weight row

typedef __attribute__((ext_vector_type(4))) float f32x4;
typedef __attribute__((ext_vector_type(8))) short short8;

#define AS1 __attribute__((address_space(1)))
#define AS3 __attribute__((address_space(3)))

static __device__ __forceinline__ unsigned short f32_to_bf16(float f) {
  union { float f; unsigned int u; } v; v.f = f;
  unsigned int r = v.u + (0x7FFFu + ((v.u >> 16) & 1u));  // round-to-nearest-even
  return (unsigned short)(r >> 16);
}

// ---------------- Pass 1: dequant packed int32 nibbles -> W bf16 [N][K] ----------------
__global__ __launch_bounds__(256) void dequant_w(const int* __restrict__ pw,
                                                 const float* __restrict__ sc,
                                                 const float* __restrict__ zp,
                                                 unsigned short* __restrict__ wb) {
  const int total = (N_DIM * KP) / 4;  // 4 int32 -> 8 bf16 per item
  for (int i = blockIdx.x * 256 + threadIdx.x; i < total; i += gridDim.x * 256) {
    int4 p = ((const int4*)pw)[i];
    int row = i >> 9;                  // (i*4)/2048 ; 2048 % 4 == 0 so no row straddle
    float s = sc[row], z = zp[row];
    int v[4] = {p.x, p.y, p.z, p.w};
    unsigned short o[8];
#pragma unroll
    for (int j = 0; j < 4; ++j) {
      o[2 * j]     = f32_to_bf16(((float)(v[j] & 15) - z) * s);
      o[2 * j + 1] = f32_to_bf16(((float)((v[j] >> 4) & 15) - z) * s);
    }
    uint4 st;
    st.x = (unsigned)o[0] | ((unsigned)o[1] << 16);
    st.y = (unsigned)o[2] | ((unsigned)o[3] << 16);
    st.z = (unsigned)o[4] | ((unsigned)o[5] << 16);
    st.w = (unsigned)o[6] | ((unsigned)o[7] << 16);
    ((uint4*)wb)[i] = st;
  }
}

// ---------------- Pass 2: x fp32 -> bf16 [M][K] ----------------
__global__ __launch_bounds__(256) void conv_x(const float* __restrict__ x,
                                              unsigned short* __restrict__ xb) {
  const int total = (M_DIM * K_DIM) / 8;
  for (int i = blockIdx.x * 256 + threadIdx.x; i < total; i += gridDim.x * 256) {
    float4 a = ((const float4*)x)[2 * i];
    float4 b = ((const float4*)x)[2 * i + 1];
    uint4 st;
    st.x = (unsigned)f32_to_bf16(a.x) | ((unsigned)f32_to_bf16(a.y) << 16);
    st.y = (unsigned)f32_to_bf16(a.z) | ((unsigned)f32_to_bf16(a.w) << 16);
    st.z = (unsigned)f32_to_bf16(b.x) | ((unsigned)f32_to_bf16(b.y) << 16);
    st.w = (unsigned)f32_to_bf16(b.z) | ((unsigned)f32_to_bf16(b.w) << 16);
    ((uint4*)xb)[i] = st;
  }
}

// ---------------- Main: bf16 MFMA GEMM, C[M,N] = Xb[M,K] @ Wb[N,K]^T ----------------
// m97 structure: 128x128 tile, BK=64, 4 waves (2x2), 4x4 fragments/wave,
// global_load_lds width=16, single-buffered LDS, 2 barriers per K-step.
#define BM 128
#define BN 128
#define BK 64
#define NT_M (M_DIM / BM)   // 32
#define NT_N (N_DIM / BN)   // 86
#define NWG  (NT_M * NT_N)  // 2752 (divisible by 8 -> simple XCD swizzle is bijective)

__global__ __launch_bounds__(256, 2) void gemm_bt(const unsigned short* __restrict__ Xb,
                                                  const unsigned short* __restrict__ Wb,
                                                  float* __restrict__ C) {
  __shared__ __align__(16) unsigned short As[BM * BK];  // 16 KiB
  __shared__ __align__(16) unsigned short Bs[BN * BK];  // 16 KiB

  const int t = threadIdx.x;
  const int bid = blockIdx.x;
  // XCD-aware swizzle (T1): consecutive swz share a B-panel in groups of 32
  const int swz = (bid & 7) * (NWG / 8) + (bid >> 3);
  const int tm = swz & 31;   // M-tile
  const int tn = swz >> 5;   // N-tile

  // staging: 1024 16B-chunks per tile; thread t owns chunks t, t+256, t+512, t+768
  const unsigned short* asrc[4];
  const unsigned short* bsrc[4];
  unsigned short* adst[4];
  unsigned short* bdst[4];
#pragma unroll
  for (int i = 0; i < 4; ++i) {
    int chunk = t + i * 256;
    int r = chunk >> 3;          // row within tile (8 chunks of 16B per 128B row)
    int c8 = chunk & 7;          // 8-element column group
    asrc[i] = Xb + (size_t)(tm * BM + r) * K_DIM + c8 * 8;
    bsrc[i] = Wb + (size_t)(tn * BN + r) * K_DIM + c8 * 8;
    adst[i] = As + chunk * 8;    // linear LDS: wave-uniform base + lane*16B  (m104 rule)
    bdst[i] = Bs + chunk * 8;
  }

  const int lane = t & 63;
  const int w = t >> 6;
  const int wm = w >> 1, wn = w & 1;     // 2x2 wave grid, 64x64 output each
  const int lr = lane & 15, lk = lane >> 4;

  int aoff[4], boff[4];
#pragma unroll
  for (int m = 0; m < 4; ++m) aoff[m] = (wm * 64 + m * 16 + lr) * BK + lk * 8;
#pragma unroll
  for (int n = 0; n < 4; ++n) boff[n] = (wn * 64 + n * 16 + lr) * BK + lk * 8;

  f32x4 acc[4][4] = {};

  for (int kt = 0; kt < K_DIM / BK; ++kt) {
    __syncthreads();   // previous compute done before overwriting LDS
#pragma unroll
    for (int i = 0; i < 4; ++i) {
      __builtin_amdgcn_global_load_lds((const AS1 void*)asrc[i], (AS3 void*)adst[i], 16, 0, 0);
      asrc[i] += BK;
    }
#pragma unroll
    for (int i = 0; i < 4; ++i) {
      __builtin_amdgcn_global_load_lds((const AS1 void*)bsrc[i], (AS3 void*)bdst[i], 16, 0, 0);
      bsrc[i] += BK;
    }
    __syncthreads();   // compiler drains vmcnt before barrier -> tile ready
#pragma unroll
    for (int kk = 0; kk < 2; ++kk) {
      short8 af[4], bf[4];
#pragma unroll
      for (int m = 0; m < 4; ++m)
        af[m] = *(const short8*)(As + aoff[m] + kk * 32);
#pragma unroll
      for (int n = 0; n < 4; ++n)
        bf[n] = *(const short8*)(Bs + boff[n] + kk * 32);
#pragma unroll
      for (int m = 0; m < 4; ++m)
#pragma unroll
        for (int n = 0; n < 4; ++n)
          acc[m][n] = __builtin_amdgcn_mfma_f32_16x16x32_bf16(af[m], bf[n], acc[m][n], 0, 0, 0);
    }
  }

  // epilogue: C/D layout col=lane&15, row=(lane>>4)*4+reg (m89/m91 verified)
  const int row0 = tm * BM + wm * 64 + lk * 4;
  const int col0 = tn * BN + wn * 64 + lr;
#pragma unroll
  for (int m = 0; m < 4; ++m)
#pragma unroll
    for (int n = 0; n < 4; ++n)
#pragma unroll
      for (int rr = 0; rr < 4; ++rr)
        C[(size_t)(row0 + m * 16 + rr) * N_DIM + col0 + n * 16] = acc[m][n][rr];
}

// ---------------- Fallback: fp32 LDS-tiled GEMM reading packed weights (used only if ws too small) ----------------
__global__ __launch_bounds__(256) void fallback_gemm(const float* __restrict__ x,
                                                     const int* __restrict__ pw,
                                                     const float* __restrict__ sc,
                                                     const float* __restrict__ zp,
                                                     float* __restrict__ out) {
  __shared__ float Xs[64][33];
  __shared__ float Ws[64][33];
  const int bid = blockIdx.x;
  const int bm = bid & 63;    // 64 M-tiles of 64
  const int bn = bid >> 6;    // 172 N-tiles of 64
  const int t = threadIdx.x;
  const int tx = t & 15, ty = t >> 4;
  float acc[4][4] = {};
  for (int k0 = 0; k0 < K_DIM; k0 += 32) {
    __syncthreads();
#pragma unroll
    for (int i = 0; i < 8; ++i) {
      int e = t + i * 256; int r = e >> 5, c = e & 31;
      Xs[r][c] = x[(size_t)(bm * 64 + r) * K_DIM + k0 + c];
    }
#pragma unroll
    for (int i = 0; i < 4; ++i) {
      int e = t + i * 256; int rr = e >> 4, jj = e & 15;
      int row = bn * 64 + rr;
      int v = pw[(size_t)row * KP + (k0 >> 1) + jj];
      float s = sc[row], z = zp[row];
      Ws[rr][2 * jj]     = ((float)(v & 15) - z) * s;
      Ws[rr][2 * jj + 1] = ((float)((v >> 4) & 15) - z) * s;
    }
    __syncthreads();
#pragma unroll
    for (int kk = 0; kk < 32; ++kk) {
      float a[4], b[4];
#pragma unroll
      for (int i2 = 0; i2 < 4; ++i2) a[i2] = Xs[ty * 4 + i2][kk];
#pragma unroll
      for (int j2 = 0; j2 < 4; ++j2) b[j2] = Ws[tx * 4 + j2][kk];
#pragma unroll
      for (int i2 = 0; i2 < 4; ++i2)
#pragma unroll
        for (int j2 = 0; j2 < 4; ++j2) acc[i2][j2] += a[i2] * b[j2];
    }
  }
#pragma unroll
  for (int i2 = 0; i2 < 4; ++i2)
#pragma unroll
    for (int j2 = 0; j2 < 4; ++j2)
      out[(size_t)(bm * 64 + ty * 4 + i2) * N_DIM + bn * 64 + tx * 4 + j2] = acc[i2][j2];
}

extern "C" void kernel_launch(void* const* d_in, const int* in_sizes, int n_in,
                              void* d_out, int out_size, void* d_ws, size_t ws_size,
                              hipStream_t stream) {
  const float* x  = (const float*)d_in[0];
  const int*   pw = (const int*)d_in[1];
  const float* sc = (const float*)d_in[2];
  const float* zp = (const float*)d_in[3];
  float* out = (float*)d_out;

  const size_t wb_bytes = (size_t)N_DIM * K_DIM * 2;  // 90,177,536
  const size_t xb_bytes = (size_t)M_DIM * K_DIM * 2;  // 33,554,432

  if (ws_size >= wb_bytes + xb_bytes) {
    unsigned short* wb = (unsigned short*)d_ws;
    unsigned short* xb = (unsigned short*)((char*)d_ws + wb_bytes);
    hipLaunchKernelGGL(dequant_w, dim3(2048), dim3(256), 0, stream, pw, sc, zp, wb);
    hipLaunchKernelGGL(conv_x,    dim3(2048), dim3(256), 0, stream, x, xb);
    hipLaunchKernelGGL(gemm_bt,   dim3(NWG),  dim3(256), 0, stream, xb, wb, out);
  } else {
    hipLaunchKernelGGL(fallback_gemm, dim3(64 * 172), dim3(256), 0, stream, x, pw, sc, zp, out);
  }
}